// Round 3
// baseline (254.704 us; speedup 1.0000x reference)
//
#include <hip/hip_runtime.h>

// DualModel3 R8: 5MB-pack (A + fcW only) + GLDS pipeline + cheap in-kernel
// decoder-B staging.
// R7 post-mortem: fc output (through ws[0..5MB]) PASSED -> pack math, swizzled
// tile image, and GLDS double-buffer pipeline are all verified. Decoder output
// failed + replay absmax 468 -> W1 pre-pack at ws[5.2..69.4MB] was OOB
// (workspace is ~5MB-class). W1 bf16 image is irreducibly 64MB => no pre-pack.
// R8: A-tiles (1MB) + fc-tiles (4MB) stay in ws (proven safe); decoder B is
// reg-staged in-kernel, engineered cheap:
//  - per-o swizzle slot = g ^ ((n>>2)&7): all 4 h-rows of one decoder share a
//    k-group -> thread reads 64B CONTIGUOUS W1 (4x f32x4), 4x ds_write_b64
//    on disjoint bank-quads per 8-lane group (<=2-way, free).
//  - async-split: B-loads + GLDS-A for kt+1 issue BEFORE the MFMA phase of kt
//    (L2/L3 latency hides under 8 MFMA + 12 ds_read); cvt+write after MFMAs.
//  - __syncthreads per iter (GLDS needs vmcnt drain, ds_writes need lgkmcnt).
// Tiling unchanged (verified): BM=128 BN=64 BK=64, 256 thr, wave 64m x 32n,
// 32x32x16 MFMA, C/D col=lane&31, row=(r&3)+8*(r>>2)+4*(lane>>5).
// A-read swizzle (mrow&7) unchanged; B-read swizzle now ((nrow>>2)&7) for BOTH
// fc and decoder (fc pack updated to match). launch_bounds(256,3): VGPR cap
// 170 -> no spill (R6 lesson), 48KB LDS -> 3 blk/CU = 12 waves/CU.

typedef __bf16 bf16_t;
typedef __bf16 bf16x4 __attribute__((ext_vector_type(4)));
typedef __bf16 bf16x8 __attribute__((ext_vector_type(8)));
typedef float  f32x4  __attribute__((ext_vector_type(4)));
typedef float  f32x16 __attribute__((ext_vector_type(16)));

#define GLDS(gp, lp) __builtin_amdgcn_global_load_lds( \
    (const __attribute__((address_space(1))) void*)(gp), \
    (__attribute__((address_space(3))) void*)(lp), 16, 0, 0)

#define WS_A_OFF 0                          // 64 tiles  x 16KB = 1 MB
#define WS_F_OFF (64 * 16384)               // 512 tiles x 8KB  = 4 MB (tot 5 MB)

// ---------------------------------------------------------------- pass 1 ----
// A image: row r (128B), slot s holds k-group g = s ^ (r&7), 8 bf16 each.
// fc image: row n (128B), slot s holds k-group g = s ^ ((n>>2)&7).
__global__ __launch_bounds__(256)
void pack_tiles(const float* __restrict__ x, const float* __restrict__ fcW,
                char* __restrict__ ws)
{
    const int tid = threadIdx.x;
    const int bid = blockIdx.x;
    if (bid < 64) {                                   // x tiles: [rg][kt] 16KB
        const int rg = bid >> 5, kt = bid & 31;
        char* dst = ws + WS_A_OFF + (size_t)bid * 16384;
        #pragma unroll
        for (int i = 0; i < 4; ++i) {
            const int gi = tid + 256 * i;
            const int r = gi >> 3, s = gi & 7, g = s ^ (r & 7);
            const float* sp = x + (size_t)(rg * 128 + r) * 2048 + kt * 64 + g * 8;
            f32x4 v0 = *(const f32x4*)sp, v1 = *(const f32x4*)(sp + 4);
            bf16x8 o;
            #pragma unroll
            for (int c = 0; c < 4; ++c) { o[c] = (bf16_t)v0[c]; o[4 + c] = (bf16_t)v1[c]; }
            *(bf16x8*)(dst + r * 128 + s * 16) = o;
        }
    } else {                                          // fcW tiles: [cg][kt] 8KB
        const int t = bid - 64;
        const int cg = t >> 5, kt = t & 31;
        char* dst = ws + WS_F_OFF + (size_t)t * 8192;
        #pragma unroll
        for (int i = 0; i < 2; ++i) {
            const int gi = tid + 256 * i;
            const int n = gi >> 3, s = gi & 7, g = s ^ ((n >> 2) & 7);
            const int c = cg * 64 + n;
            bf16x8 o;
            if (c < 1000) {
                const float* sp = fcW + (size_t)c * 2048 + kt * 64 + g * 8;
                f32x4 v0 = *(const f32x4*)sp, v1 = *(const f32x4*)(sp + 4);
                #pragma unroll
                for (int cc = 0; cc < 4; ++cc) { o[cc] = (bf16_t)v0[cc]; o[4 + cc] = (bf16_t)v1[cc]; }
            } else {
                #pragma unroll
                for (int cc = 0; cc < 8; ++cc) o[cc] = (bf16_t)0.f;
            }
            *(bf16x8*)(dst + n * 128 + s * 16) = o;
        }
    }
}

// ---------------------------------------------------------------- pass 2 ----
__global__ __launch_bounds__(256, 3)    // 12 waves/CU; VGPR cap ~170 (no spill)
void fused_dual(const char* __restrict__ ws,
                const float* __restrict__ W1,   // [4096,2048,4] fp32
                const float* __restrict__ fcb,
                const float* __restrict__ b1,
                const float* __restrict__ W2,
                const float* __restrict__ b2,
                float* __restrict__ out)        // x1[256*1000] ++ x2[256*4096]
{
    __shared__ __align__(16) char lds[2][24576];   // [buf][A 16KB | B 8KB]

    const int tid  = threadIdx.x;
    const int lane = tid & 63, w = tid >> 6;       // 4 waves
    const int l31  = lane & 31, half = lane >> 5;

    // XCD swizzle: 544 % 8 == 0 -> bijective; row-siblings adjacent (L2 reuse).
    const int idx = blockIdx.x;
    const int wid = (idx & 7) * 68 + (idx >> 3);
    const int cg  = wid >> 1, rg = wid & 1, m0 = rg * 128;
    const bool is_fc = (cg < 16);
    const int c0  = (is_fc ? cg : cg - 16) * 64;
    const int dcg = is_fc ? 0 : (cg - 16);

    const char* aT = ws + WS_A_OFF + (size_t)rg * 32 * 16384;   // + kt*16384
    const char* bT = ws + WS_F_OFF + (size_t)cg * 32 * 8192;    // fc only

    const int lo = lane * 16;   // per-lane global offset; GLDS dest wave-uniform

    // ---- decoder B staging map ----
    // thread: u=tid&127, hi=tid>>7; oloc=u>>3 (o in panel), gg=u&7 (k-group).
    // slot = gg ^ (oloc&7)  ==  read's g ^ ((n>>2)&7) with g=gg, n=4*oloc+h.
    // loads: W1[o0+oloc][k0+gg*8+hi*4+j][0..3], j=0..3  (64B contiguous).
    // writes: row n=4*oloc+h, byte n*128 + slot*16 + hi*8 (b64).
    const int u    = tid & 127, hi = tid >> 7;
    const int oloc = u >> 3, gg = u & 7;
    const int slot = gg ^ (oloc & 7);
    const float* w1Base = W1 + (size_t)(dcg * 16 + oloc) * 8192
                             + (gg * 8 + hi * 4) * 4;
    const int wbase = (4 * oloc) * 128 + slot * 16 + hi * 8;

    f32x4 bReg[4];

    auto B_LOAD = [&](int kt) {
        const float* p = w1Base + kt * 256;                 // 64 k * 4 floats
        #pragma unroll
        for (int j = 0; j < 4; ++j) bReg[j] = *(const f32x4*)(p + j * 4);
    };
    auto B_WRITE = [&](int pbuf) {
        char* lB = &lds[pbuf][16384];
        #pragma unroll
        for (int h = 0; h < 4; ++h) {
            bf16x4 v;
            #pragma unroll
            for (int j = 0; j < 4; ++j) v[j] = (bf16_t)bReg[j][h];
            *(bf16x4*)(lB + wbase + h * 128) = v;
        }
    };
    auto GLDS_A = [&](int kt, int pbuf) {
        char* lA = &lds[pbuf][0];
        const char* ga = aT + kt * 16384 + w * 4096;
        #pragma unroll
        for (int i = 0; i < 4; ++i)
            GLDS(ga + i * 1024 + lo, lA + w * 4096 + i * 1024);
    };
    auto GLDS_B_FC = [&](int kt, int pbuf) {
        char* lB = &lds[pbuf][16384];
        const char* gb = bT + kt * 8192 + w * 2048;
        #pragma unroll
        for (int i = 0; i < 2; ++i)
            GLDS(gb + i * 1024 + lo, lB + w * 2048 + i * 1024);
    };

    const int mh = (w & 1) * 64, nh = (w >> 1) * 32;   // wave tile 64m x 32n
    f32x16 acc[2];
    #pragma unroll
    for (int i = 0; i < 2; ++i)
        #pragma unroll
        for (int r = 0; r < 16; ++r) acc[i][r] = 0.f;

    // prologue: tile 0 into buf 0
    if (is_fc) {
        GLDS_A(0, 0); GLDS_B_FC(0, 0);
    } else {
        B_LOAD(0); GLDS_A(0, 0); B_WRITE(0);
    }
    __syncthreads();

    const int nrow = nh + l31;
    const int bro  = nrow * 128 + (((nrow >> 2) & 7) << 4);  // fold B XOR term
    for (int kt = 0; kt < 32; ++kt) {
        const int p = kt & 1;
        if (kt < 31) {                       // issue next tile BEFORE MFMA phase
            if (is_fc) { GLDS_A(kt + 1, p ^ 1); GLDS_B_FC(kt + 1, p ^ 1); }
            else       { B_LOAD(kt + 1); GLDS_A(kt + 1, p ^ 1); }
        }
        const char* lA = &lds[p][0];
        const char* lB = &lds[p][16384];
        #pragma unroll
        for (int ks = 0; ks < 4; ++ks) {
            const int g = ks * 2 + half;
            bf16x8 bf = *(const bf16x8*)(lB + (bro ^ (g << 4)));
            #pragma unroll
            for (int i = 0; i < 2; ++i) {
                const int mrow = mh + i * 32 + l31;
                bf16x8 af = *(const bf16x8*)(lA + mrow * 128 + ((g ^ (mrow & 7)) << 4));
                acc[i] = __builtin_amdgcn_mfma_f32_32x32x16_bf16(af, bf, acc[i], 0, 0, 0);
            }
        }
        if (!is_fc && kt < 31) B_WRITE(p ^ 1);  // cvt+write after MFMAs
        __syncthreads();                        // vmcnt+lgkmcnt drain + barrier
    }

    // ---- epilogue ----  C/D: col=lane&31, row=(r&3)+8*(r>>2)+4*half
    if (is_fc) {
        const int c = c0 + nh + l31;
        if (c < 1000) {
            const float bias = fcb[c];
            #pragma unroll
            for (int i = 0; i < 2; ++i)
            #pragma unroll
            for (int r = 0; r < 16; ++r) {
                const int m = m0 + mh + i * 32 + (r & 3) + 8 * (r >> 2) + 4 * half;
                out[m * 1000 + c] = acc[i][r] + bias;
            }
        }
    } else {
        float* x2 = out + 256 * 1000;
        const int d = cg - 16;                    // decoder col-panel
        const int n_glob = c0 + nh + l31;
        const float b1v = b1[n_glob], w2v = W2[n_glob];
        const float b2v = b2[n_glob >> 2];
        float* xs = (float*)lds;                  // [128 rows][16 o] fp32 = 8KB
        const int o_loc = (nh + l31) >> 2;
        #pragma unroll
        for (int i = 0; i < 2; ++i)
        #pragma unroll
        for (int r = 0; r < 16; ++r) {
            float h = acc[i][r] + b1v;
            h = (h >= 0.f) ? h : 0.1f * h;        // leaky relu
            float wv = h * w2v;
            wv += __shfl_xor(wv, 1, 64);          // decoder's 4 h-cols
            wv += __shfl_xor(wv, 2, 64);
            if ((lane & 3) == 0) {
                const int row = mh + i * 32 + (r & 3) + 8 * (r >> 2) + 4 * half;
                xs[row * 16 + o_loc] = wv + b2v;
            }
        }
        __syncthreads();
        #pragma unroll
        for (int j = 0; j < 2; ++j) {
            const int row = (tid >> 2) + 64 * j, part = tid & 3;
            f32x4 v = *(const f32x4*)(xs + row * 16 + part * 4);
            *(f32x4*)(x2 + (m0 + row) * 4096 + d * 16 + part * 4) = v;
        }
    }
}

extern "C" void kernel_launch(void* const* d_in, const int* in_sizes, int n_in,
                              void* d_out, int out_size, void* d_ws, size_t ws_size,
                              hipStream_t stream)
{
    (void)in_sizes; (void)n_in; (void)out_size; (void)ws_size;
    const float* x   = (const float*)d_in[0];
    const float* fcW = (const float*)d_in[1];
    const float* fcb = (const float*)d_in[2];
    const float* W1  = (const float*)d_in[3];
    const float* b1  = (const float*)d_in[4];
    const float* W2  = (const float*)d_in[5];
    const float* b2  = (const float*)d_in[6];
    char* ws = (char*)d_ws;                       // needs 5 MB (proven R7-safe)
    pack_tiles<<<576, 256, 0, stream>>>(x, fcW, ws);
    fused_dual<<<544, 256, 0, stream>>>(ws, W1, fcb, b1, W2, b2, (float*)d_out);
}